// Round 1
// baseline (786.480 us; speedup 1.0000x reference)
//
#include <hip/hip_runtime.h>
#include <hip/hip_bf16.h>
#include <stdint.h>

// Problem constants: x [4,2048,2048] fp32, W [8192,2048] fp32, gamma [2048] fp32
// out [4,2048,8192] fp32.  C[M,N] = rmsnorm(x)[M,K] . Wq[N,K]^T * scale
#define M_ROWS 8192
#define K_DIM  2048
#define N_DIM  8192
#define W_ELEMS (N_DIM * K_DIM)   // 16777216
#define X_ELEMS (M_ROWS * K_DIM)  // 16777216

typedef __bf16 v8bf __attribute__((ext_vector_type(8)));
typedef float  v4f  __attribute__((ext_vector_type(4)));

// bf16 storage as raw ushort; deterministic RNE convert
__device__ inline unsigned short f2bf(float f) {
  uint32_t u = __builtin_bit_cast(uint32_t, f);
  uint32_t r = (u + 0x7fffu + ((u >> 16) & 1u)) >> 16;
  return (unsigned short)r;
}

__device__ inline void async_copy16(const void* g, void* l) {
  __builtin_amdgcn_global_load_lds(
      (const __attribute__((address_space(1))) void*)g,
      (__attribute__((address_space(3))) void*)l, 16, 0, 0);
}

// ---------------- Kernel 1: sum(|W|) with double accumulation ----------------
__global__ __launch_bounds__(256) void absum_kernel(const float* __restrict__ W,
                                                    double* __restrict__ out) {
  int tid = blockIdx.x * 256 + threadIdx.x;
  int stride = gridDim.x * 256;
  const float4* W4 = (const float4*)W;
  const int n4 = W_ELEMS / 4;
  double acc = 0.0;
  for (int i = tid; i < n4; i += stride) {
    float4 v = W4[i];
    acc += (double)fabsf(v.x) + (double)fabsf(v.y) +
           (double)fabsf(v.z) + (double)fabsf(v.w);
  }
  for (int off = 32; off > 0; off >>= 1) acc += __shfl_down(acc, off);
  __shared__ double wsum[4];
  int lane = threadIdx.x & 63, wid = threadIdx.x >> 6;
  if (lane == 0) wsum[wid] = acc;
  __syncthreads();
  if (threadIdx.x == 0) {
    atomicAdd(out, wsum[0] + wsum[1] + wsum[2] + wsum[3]);
  }
}

// ---------------- Kernel 2: RMSNorm row -> bf16 ----------------
__global__ __launch_bounds__(256) void rmsnorm_kernel(const float* __restrict__ X,
                                                      const float* __restrict__ gamma,
                                                      unsigned short* __restrict__ Xn) {
  const int row = blockIdx.x;
  const int t = threadIdx.x;
  const float4* xr = (const float4*)(X + (size_t)row * K_DIM);
  float4 a = xr[t * 2];
  float4 b = xr[t * 2 + 1];
  float ss = a.x * a.x + a.y * a.y + a.z * a.z + a.w * a.w +
             b.x * b.x + b.y * b.y + b.z * b.z + b.w * b.w;
  for (int off = 32; off > 0; off >>= 1) ss += __shfl_down(ss, off);
  __shared__ float wsum[4];
  int lane = t & 63, wid = t >> 6;
  if (lane == 0) wsum[wid] = ss;
  __syncthreads();
  float total = wsum[0] + wsum[1] + wsum[2] + wsum[3];
  float inv = 1.0f / sqrtf(total * (1.0f / (float)K_DIM) + 1e-6f);
  const float4* gr = (const float4*)gamma;
  float4 g0 = gr[t * 2];
  float4 g1 = gr[t * 2 + 1];
  union { unsigned short h[8]; uint4 u; } p;
  p.h[0] = f2bf((a.x * inv) * g0.x);
  p.h[1] = f2bf((a.y * inv) * g0.y);
  p.h[2] = f2bf((a.z * inv) * g0.z);
  p.h[3] = f2bf((a.w * inv) * g0.w);
  p.h[4] = f2bf((b.x * inv) * g1.x);
  p.h[5] = f2bf((b.y * inv) * g1.y);
  p.h[6] = f2bf((b.z * inv) * g1.z);
  p.h[7] = f2bf((b.w * inv) * g1.w);
  ((uint4*)(Xn + (size_t)row * K_DIM))[t] = p.u;
}

// ---------------- Kernel 3: ternary quantize W -> bf16 {-1,0,1} ----------------
__global__ __launch_bounds__(256) void quant_kernel(const float* __restrict__ W,
                                                    const double* __restrict__ sum_ws,
                                                    unsigned short* __restrict__ Wq) {
  float s = (float)fmax(sum_ws[0] * (1.0 / (double)W_ELEMS), 1e-5);
  size_t idx = ((size_t)blockIdx.x * 256 + threadIdx.x) * 8;
  const float4* w4 = (const float4*)(W + idx);
  float4 a = w4[0];
  float4 b = w4[1];
  union { unsigned short h[8]; uint4 u; } p;
  p.h[0] = f2bf(rintf(fminf(1.f, fmaxf(-1.f, a.x / s))));
  p.h[1] = f2bf(rintf(fminf(1.f, fmaxf(-1.f, a.y / s))));
  p.h[2] = f2bf(rintf(fminf(1.f, fmaxf(-1.f, a.z / s))));
  p.h[3] = f2bf(rintf(fminf(1.f, fmaxf(-1.f, a.w / s))));
  p.h[4] = f2bf(rintf(fminf(1.f, fmaxf(-1.f, b.x / s))));
  p.h[5] = f2bf(rintf(fminf(1.f, fmaxf(-1.f, b.y / s))));
  p.h[6] = f2bf(rintf(fminf(1.f, fmaxf(-1.f, b.z / s))));
  p.h[7] = f2bf(rintf(fminf(1.f, fmaxf(-1.f, b.w / s))));
  *(uint4*)(Wq + idx) = p.u;
}

// ---------------- Kernel 4: bf16 MFMA GEMM (m97 structure) ----------------
// C[M,N] = A[M,K] . B[N,K]^T * s   — 128x128 block tile, BK=32,
// 4 waves, each wave 64x64 via 4x4 grid of 16x16x32 MFMAs.
__global__ __launch_bounds__(256) void gemm_kernel(
    const unsigned short* __restrict__ A,   // x_norm bf16 [M,K]
    const unsigned short* __restrict__ B,   // wq bf16 [N,K]
    const double* __restrict__ sum_ws,
    float* __restrict__ C) {
  __shared__ __align__(16) unsigned short lds_a[128 * 32];
  __shared__ __align__(16) unsigned short lds_b[128 * 32];

  const int tid = threadIdx.x;
  const int lane = tid & 63;
  const int wave = tid >> 6;
  const int m0 = blockIdx.y * 128;
  const int n0 = blockIdx.x * 128;
  const int wm = (wave & 1) * 64;
  const int wn = (wave >> 1) * 64;

  v4f acc[4][4] = {};

  // staging: each wave stages 2 chunks of 1 KiB (16 rows x 32 cols bf16) for A and B
  const int srow = lane >> 2;          // 0..15 row within chunk
  const int scol = (lane & 3) * 8;     // 0,8,16,24 element col

  for (int k0 = 0; k0 < K_DIM; k0 += 32) {
#pragma unroll
    for (int j = 0; j < 2; ++j) {
      const int chunk = wave * 2 + j;  // 0..7, wave-uniform
      const unsigned short* ga =
          A + (size_t)(m0 + chunk * 16 + srow) * K_DIM + (k0 + scol);
      async_copy16(ga, (char*)lds_a + chunk * 1024);
      const unsigned short* gb =
          B + (size_t)(n0 + chunk * 16 + srow) * K_DIM + (k0 + scol);
      async_copy16(gb, (char*)lds_b + chunk * 1024);
    }
    __syncthreads();  // drains vmcnt (global_load_lds) + barrier

    v8bf af[4], bfr[4];
#pragma unroll
    for (int t = 0; t < 4; ++t) {
      af[t]  = *(const v8bf*)(lds_a + (wm + t * 16 + (lane & 15)) * 32 + (lane >> 4) * 8);
      bfr[t] = *(const v8bf*)(lds_b + (wn + t * 16 + (lane & 15)) * 32 + (lane >> 4) * 8);
    }
#pragma unroll
    for (int tm = 0; tm < 4; ++tm)
#pragma unroll
      for (int tn = 0; tn < 4; ++tn)
        acc[tm][tn] = __builtin_amdgcn_mfma_f32_16x16x32_bf16(
            af[tm], bfr[tn], acc[tm][tn], 0, 0, 0);
    __syncthreads();
  }

  const float s = (float)fmax(sum_ws[0] * (1.0 / (double)W_ELEMS), 1e-5);
  const int crow = m0 + wm + (lane >> 4) * 4;
  const int ccol = n0 + wn + (lane & 15);
#pragma unroll
  for (int tm = 0; tm < 4; ++tm) {
#pragma unroll
    for (int tn = 0; tn < 4; ++tn) {
#pragma unroll
      for (int r = 0; r < 4; ++r) {
        const int row = crow + tm * 16 + r;
        const int col = ccol + tn * 16;
        C[(size_t)row * N_DIM + col] = acc[tm][tn][r] * s;
      }
    }
  }
}

extern "C" void kernel_launch(void* const* d_in, const int* in_sizes, int n_in,
                              void* d_out, int out_size, void* d_ws, size_t ws_size,
                              hipStream_t stream) {
  const float* x = (const float*)d_in[0];
  const float* w = (const float*)d_in[1];
  const float* gamma = (const float*)d_in[2];
  float* out = (float*)d_out;

  // ws layout: [0,16) double abs-sum accumulator; then x_norm bf16 (32MB); then wq bf16 (32MB)
  double* ws_sum = (double*)d_ws;
  unsigned short* xn = (unsigned short*)((char*)d_ws + 16);
  unsigned short* wq = (unsigned short*)((char*)d_ws + 16 + (size_t)X_ELEMS * 2);

  hipMemsetAsync(d_ws, 0, 16, stream);
  absum_kernel<<<1024, 256, 0, stream>>>(w, ws_sum);
  rmsnorm_kernel<<<M_ROWS, 256, 0, stream>>>(x, gamma, xn);
  quant_kernel<<<W_ELEMS / (256 * 8), 256, 0, stream>>>(w, ws_sum, wq);
  dim3 grid(N_DIM / 128, M_ROWS / 128);
  gemm_kernel<<<grid, 256, 0, stream>>>(xn, wq, ws_sum, out);
}

// Round 2
// 713.580 us; speedup vs baseline: 1.1022x; 1.1022x over previous
//
#include <hip/hip_runtime.h>
#include <hip/hip_bf16.h>
#include <stdint.h>

// x [4,2048,2048] fp32, W [8192,2048] fp32, gamma [2048] fp32 -> out [4,2048,8192] fp32
// C[M,N] = rmsnorm(x)[M,K] . Wq[N,K]^T * scale
#define M_ROWS 8192
#define K_DIM  2048
#define N_DIM  8192
#define W_ELEMS (N_DIM * K_DIM)
#define X_ELEMS (M_ROWS * K_DIM)

typedef __bf16 v8bf __attribute__((ext_vector_type(8)));
typedef float  v4f  __attribute__((ext_vector_type(4)));

__device__ inline unsigned short f2bf(float f) {
  uint32_t u = __builtin_bit_cast(uint32_t, f);
  uint32_t r = (u + 0x7fffu + ((u >> 16) & 1u)) >> 16;
  return (unsigned short)r;
}

__device__ inline void async_copy16(const void* g, void* l) {
  __builtin_amdgcn_global_load_lds(
      (const __attribute__((address_space(1))) void*)g,
      (__attribute__((address_space(3))) void*)l, 16, 0, 0);
}

// ---------------- Kernel 1: sum(|W|), double accumulation ----------------
__global__ __launch_bounds__(256) void absum_kernel(const float* __restrict__ W,
                                                    double* __restrict__ out) {
  int tid = blockIdx.x * 256 + threadIdx.x;
  int stride = gridDim.x * 256;
  const float4* W4 = (const float4*)W;
  const int n4 = W_ELEMS / 4;
  double acc = 0.0;
  for (int i = tid; i < n4; i += stride) {
    float4 v = W4[i];
    acc += (double)fabsf(v.x) + (double)fabsf(v.y) +
           (double)fabsf(v.z) + (double)fabsf(v.w);
  }
  for (int off = 32; off > 0; off >>= 1) acc += __shfl_down(acc, off);
  __shared__ double wsum[4];
  int lane = threadIdx.x & 63, wid = threadIdx.x >> 6;
  if (lane == 0) wsum[wid] = acc;
  __syncthreads();
  if (threadIdx.x == 0) atomicAdd(out, wsum[0] + wsum[1] + wsum[2] + wsum[3]);
}

// ---------------- Kernel 2: RMSNorm row -> bf16 ----------------
__global__ __launch_bounds__(256) void rmsnorm_kernel(const float* __restrict__ X,
                                                      const float* __restrict__ gamma,
                                                      unsigned short* __restrict__ Xn) {
  const int row = blockIdx.x;
  const int t = threadIdx.x;
  const float4* xr = (const float4*)(X + (size_t)row * K_DIM);
  float4 a = xr[t * 2];
  float4 b = xr[t * 2 + 1];
  float ss = a.x * a.x + a.y * a.y + a.z * a.z + a.w * a.w +
             b.x * b.x + b.y * b.y + b.z * b.z + b.w * b.w;
  for (int off = 32; off > 0; off >>= 1) ss += __shfl_down(ss, off);
  __shared__ float wsum[4];
  int lane = t & 63, wid = t >> 6;
  if (lane == 0) wsum[wid] = ss;
  __syncthreads();
  float total = wsum[0] + wsum[1] + wsum[2] + wsum[3];
  float inv = 1.0f / sqrtf(total * (1.0f / (float)K_DIM) + 1e-6f);
  const float4* gr = (const float4*)gamma;
  float4 g0 = gr[t * 2];
  float4 g1 = gr[t * 2 + 1];
  union { unsigned short h[8]; uint4 u; } p;
  p.h[0] = f2bf((a.x * inv) * g0.x);
  p.h[1] = f2bf((a.y * inv) * g0.y);
  p.h[2] = f2bf((a.z * inv) * g0.z);
  p.h[3] = f2bf((a.w * inv) * g0.w);
  p.h[4] = f2bf((b.x * inv) * g1.x);
  p.h[5] = f2bf((b.y * inv) * g1.y);
  p.h[6] = f2bf((b.z * inv) * g1.z);
  p.h[7] = f2bf((b.w * inv) * g1.w);
  ((uint4*)(Xn + (size_t)row * K_DIM))[t] = p.u;
}

// ---------------- Kernel 3: ternary quantize W -> bf16 {-1,0,1} ----------------
__global__ __launch_bounds__(256) void quant_kernel(const float* __restrict__ W,
                                                    const double* __restrict__ sum_ws,
                                                    unsigned short* __restrict__ Wq) {
  float s = (float)fmax(sum_ws[0] * (1.0 / (double)W_ELEMS), 1e-5);
  size_t idx = ((size_t)blockIdx.x * 256 + threadIdx.x) * 8;
  const float4* w4 = (const float4*)(W + idx);
  float4 a = w4[0];
  float4 b = w4[1];
  union { unsigned short h[8]; uint4 u; } p;
  p.h[0] = f2bf(rintf(fminf(1.f, fmaxf(-1.f, a.x / s))));
  p.h[1] = f2bf(rintf(fminf(1.f, fmaxf(-1.f, a.y / s))));
  p.h[2] = f2bf(rintf(fminf(1.f, fmaxf(-1.f, a.z / s))));
  p.h[3] = f2bf(rintf(fminf(1.f, fmaxf(-1.f, a.w / s))));
  p.h[4] = f2bf(rintf(fminf(1.f, fmaxf(-1.f, b.x / s))));
  p.h[5] = f2bf(rintf(fminf(1.f, fmaxf(-1.f, b.y / s))));
  p.h[6] = f2bf(rintf(fminf(1.f, fmaxf(-1.f, b.z / s))));
  p.h[7] = f2bf(rintf(fminf(1.f, fmaxf(-1.f, b.w / s))));
  *(uint4*)(Wq + idx) = p.u;
}

// ---------------- Kernel 4: bf16 MFMA GEMM, BK=64, XOR-swizzled LDS ----------------
// 128x128 block tile, 4 waves each 64x64 via 4x4 grid of 16x16x32 MFMAs, 2 k-subs.
// LDS layout: row stride 128B; element (row, k): cg = k>>3, slot = cg ^ (row & 7),
// byte = row*128 + slot*16 + (k&7)*2.  Conflict-free (2-way max per bank quad).
// MFMA issued as mfma(b_frag, a_frag) so the 4 acc regs hold 4 consecutive N
// columns -> float4 C stores (verified layout: row=(lane>>4)*4+reg, col=lane&15).
__global__ __launch_bounds__(256, 3) void gemm_kernel(
    const unsigned short* __restrict__ A,   // x_norm bf16 [M,K]
    const unsigned short* __restrict__ B,   // wq bf16 [N,K]
    const double* __restrict__ sum_ws,
    float* __restrict__ C) {
  __shared__ __align__(16) unsigned short lds_a[128 * 64];
  __shared__ __align__(16) unsigned short lds_b[128 * 64];

  const int tid = threadIdx.x;
  const int lane = tid & 63;
  const int wave = tid >> 6;

  // 4x4 supertile block swizzle for L2/LLC locality
  const int lin = blockIdx.x;
  const int wi = lin & 15;
  const int st = lin >> 4;
  const int mb = (st >> 4) * 4 + (wi >> 2);
  const int nb = (st & 15) * 4 + (wi & 3);
  const int m0 = mb * 128;
  const int n0 = nb * 128;
  const int wm = (wave & 1) * 64;
  const int wn = (wave >> 1) * 64;

  const float s = (float)fmax(sum_ws[0] * (1.0 / (double)W_ELEMS), 1e-5);

  v4f acc[4][4] = {};

  // staging: chunk = 8 rows x 128B = 1KB; lane l -> lds byte chunk*1024 + l*16
  // source element: row = chunk*8 + (l>>3), colgroup = (l&7) ^ ((l>>3)&7)
  const int srow_in = lane >> 3;                 // 0..7 row within chunk
  const int scg = (lane & 7) ^ (srow_in & 7);    // XOR-swizzled source colgroup

  for (int k0 = 0; k0 < K_DIM; k0 += 64) {
#pragma unroll
    for (int j = 0; j < 4; ++j) {
      const int chunk = wave * 4 + j;            // 0..15, wave-uniform
      const int row = chunk * 8 + srow_in;       // 0..127
      const unsigned short* ga = A + (size_t)(m0 + row) * K_DIM + (k0 + scg * 8);
      async_copy16(ga, (char*)lds_a + chunk * 1024);
      const unsigned short* gb = B + (size_t)(n0 + row) * K_DIM + (k0 + scg * 8);
      async_copy16(gb, (char*)lds_b + chunk * 1024);
    }
    __syncthreads();

#pragma unroll
    for (int sub = 0; sub < 2; ++sub) {
      v8bf af[4], bfr[4];
      const int kg = sub * 4 + (lane >> 4);      // colgroup 0..7
#pragma unroll
      for (int t = 0; t < 4; ++t) {
        const int arow = wm + t * 16 + (lane & 15);
        af[t] = *(const v8bf*)((const char*)lds_a + arow * 128 + ((kg ^ (arow & 7)) << 4));
        const int brow = wn + t * 16 + (lane & 15);
        bfr[t] = *(const v8bf*)((const char*)lds_b + brow * 128 + ((kg ^ (brow & 7)) << 4));
      }
#pragma unroll
      for (int tm = 0; tm < 4; ++tm)
#pragma unroll
        for (int tn = 0; tn < 4; ++tn)
          acc[tm][tn] = __builtin_amdgcn_mfma_f32_16x16x32_bf16(
              bfr[tn], af[tm], acc[tm][tn], 0, 0, 0);  // swapped: N in rows, M in cols
    }
    __syncthreads();
  }

  // epilogue: lane holds, per (tm,tn): M col = lane&15, N rows = (lane>>4)*4 + reg
  const int mcol = m0 + wm + (lane & 15);
  const int nrow = n0 + wn + (lane >> 4) * 4;
#pragma unroll
  for (int tm = 0; tm < 4; ++tm) {
#pragma unroll
    for (int tn = 0; tn < 4; ++tn) {
      const int m = mcol + tm * 16;
      const int n = nrow + tn * 16;
      float4 v;
      v.x = acc[tm][tn][0] * s;
      v.y = acc[tm][tn][1] * s;
      v.z = acc[tm][tn][2] * s;
      v.w = acc[tm][tn][3] * s;
      *(float4*)&C[(size_t)m * N_DIM + n] = v;
    }
  }
}

extern "C" void kernel_launch(void* const* d_in, const int* in_sizes, int n_in,
                              void* d_out, int out_size, void* d_ws, size_t ws_size,
                              hipStream_t stream) {
  const float* x = (const float*)d_in[0];
  const float* w = (const float*)d_in[1];
  const float* gamma = (const float*)d_in[2];
  float* out = (float*)d_out;

  double* ws_sum = (double*)d_ws;
  unsigned short* xn = (unsigned short*)((char*)d_ws + 16);
  unsigned short* wq = (unsigned short*)((char*)d_ws + 16 + (size_t)X_ELEMS * 2);

  hipMemsetAsync(d_ws, 0, 16, stream);
  absum_kernel<<<2048, 256, 0, stream>>>(w, ws_sum);
  rmsnorm_kernel<<<M_ROWS, 256, 0, stream>>>(x, gamma, xn);
  quant_kernel<<<W_ELEMS / (256 * 8), 256, 0, stream>>>(w, ws_sum, wq);
  gemm_kernel<<<4096, 256, 0, stream>>>(xn, wq, ws_sum, out);
}